// Round 5
// baseline (622.037 us; speedup 1.0000x reference)
//
#include <hip/hip_runtime.h>

// B=8, C=256, K=64, H=W=64, HW=4096
using bf16x8 = __attribute__((ext_vector_type(8))) short;
using f16x8  = __attribute__((ext_vector_type(8))) _Float16;
using f32x4  = __attribute__((ext_vector_type(4))) float;

#define DEVI static __device__ __forceinline__

DEVI unsigned short f2bf(float f){
  unsigned u = __builtin_bit_cast(unsigned, f);
  u += 0x7fffu + ((u >> 16) & 1u);
  return (unsigned short)(u >> 16);
}
DEVI unsigned short f2h(float f){
  _Float16 h = (_Float16)f;
  return __builtin_bit_cast(unsigned short, h);
}
DEVI f32x4 zf4(){ f32x4 z; z[0]=0.f; z[1]=0.f; z[2]=0.f; z[3]=0.f; return z; }

// ---------------------------------------------------------------------------
// k_prep: transpose 1x1 weights to [c][k]; pack 3x3 weights to [tau][o][c] bf16
// ---------------------------------------------------------------------------
__global__ __launch_bounds__(256) void k_prep(
    const float* __restrict__ top_w, const float* __restrict__ cen_w,
    const float* __restrict__ bot_w, const float* __restrict__ out_w,
    float* __restrict__ wTt, float* __restrict__ wTc,
    unsigned short* __restrict__ apb, unsigned short* __restrict__ apo){
  int i = blockIdx.x * 256 + threadIdx.x;
  if (i < 64 * 256){
    int c = i >> 6, k = i & 63;
    wTt[i] = top_w[k * 256 + c];
    wTc[i] = cen_w[k * 256 + c];
  }
  if (i < 9 * 256 * 256){
    int tau = i >> 16, oc = i & 65535;   // oc = o*256+c
    apb[i] = f2bf(bot_w[oc * 9 + tau]);
    apo[i] = f2bf(out_w[oc * 9 + tau]);
  }
}

// ---------------------------------------------------------------------------
// k_topcenter: top/center = W[64,256] @ x[256,4096] per batch, fp32 VALU,
// stored transposed [n][k] as fp16. top pre-scaled by log2(e) so the
// softmax exp becomes a single v_exp_f32 (exp2) in k_pv.
// ---------------------------------------------------------------------------
__global__ __launch_bounds__(256) void k_topcenter(
    const float* __restrict__ x,
    const float* __restrict__ wTt, const float* __restrict__ wTc,
    const float* __restrict__ top_b, const float* __restrict__ cen_b,
    unsigned short* __restrict__ tT16, unsigned short* __restrict__ cT16){
  __shared__ float xs[16][256];
  int b = blockIdx.z, z = blockIdx.y, nt = blockIdx.x;
  int t = threadIdx.x;
  int n = nt * 256 + t;
  const float* wT   = z ? wTc : wTt;
  const float* bias = z ? cen_b : top_b;
  unsigned short* o16 = z ? cT16 : tT16;
  const float scale = z ? 1.0f : 1.4426950408889634f;   // log2(e) folded into top
  const float* xb = x + ((size_t)b << 20);

  float acc[64];
  #pragma unroll
  for (int k = 0; k < 64; k++) acc[k] = 0.f;

  for (int cc = 0; cc < 256; cc += 16){
    __syncthreads();
    #pragma unroll
    for (int r = 0; r < 16; r++)
      xs[r][t] = xb[((size_t)(cc + r) << 12) + nt * 256 + t];
    __syncthreads();
    #pragma unroll
    for (int r = 0; r < 16; r++){
      float xv = xs[r][t];
      const float* wr = wT + (cc + r) * 64;   // uniform -> scalar loads
      #pragma unroll
      for (int k = 0; k < 64; k++) acc[k] = fmaf(wr[k], xv, acc[k]);
    }
  }
  size_t base = (((size_t)b << 12) + n) * 64;
  #pragma unroll
  for (int k8 = 0; k8 < 64; k8 += 8){
    bf16x8 v8;
    #pragma unroll
    for (int j = 0; j < 8; j++)
      v8[j] = (short)f2h((acc[k8 + j] + bias[k8 + j]) * scale);
    *(bf16x8*)(o16 + base + k8) = v8;
  }
}

// ---------------------------------------------------------------------------
// k_trans: channels-first fp32 (+ optional (U0+U1)/Z residual) -> ch-last bf16
// ---------------------------------------------------------------------------
__global__ __launch_bounds__(256) void k_trans(
    const float* __restrict__ x, const float* __restrict__ U0,
    const float* __restrict__ U1, const float* __restrict__ Z,
    unsigned short* __restrict__ ocl){
  __shared__ float tile[32][33];
  int b = blockIdx.z, ct = blockIdx.y, pt = blockIdx.x;
  int tx = threadIdx.x & 31, ty = threadIdx.x >> 5;
  size_t bo = (size_t)b << 20;
  int c0 = ct * 32, p0 = pt * 32;
  float invZ = (U0 != nullptr) ? (1.0f / Z[b]) : 0.0f;
  #pragma unroll
  for (int q = 0; q < 4; q++){
    int c = c0 + ty + q * 8;
    size_t idx = bo + ((size_t)c << 12) + p0 + tx;
    float v = x[idx];
    if (U0){
      float u = U0[idx];
      if (U1) u += U1[idx];
      v = fmaf(u, invZ, v);
    }
    tile[ty + q * 8][tx] = v;
  }
  __syncthreads();
  #pragma unroll
  for (int q = 0; q < 4; q++){
    int p = p0 + ty + q * 8;
    ocl[bo + ((size_t)p << 8) + c0 + tx] = f2bf(tile[tx][ty + q * 8]);
  }
}

// ---------------------------------------------------------------------------
// k_conv3 v3: 3x3 SAME conv, halo-row staging reused across 9 taps,
// T14 async-stage: next chunk's global loads issue BEFORE the MFMA section.
// Block: (b, image row h, o-half). 256 thr / 4 waves; wave owns 32 o.
// ---------------------------------------------------------------------------
template<int OUTF32>
__global__ __launch_bounds__(256, 4) void k_conv3(
    const unsigned short* __restrict__ incl,
    const unsigned short* __restrict__ ap,
    const float* __restrict__ bias, void* __restrict__ outp){
  __shared__ unsigned short Xs[3][64][72];   // [halo row][w][c-chunk], 144B rows
  int bid = blockIdx.x;
  int b = bid & 7, h = (bid >> 3) & 63, oh = bid >> 9;
  int t = threadIdx.x, wv = t >> 6, l = t & 63, lr = l & 15, g = l >> 4;
  int o0 = oh * 128 + wv * 32;
  const unsigned short* inb = incl + ((size_t)b << 20);

  f32x4 acc[2][4];
  #pragma unroll
  for (int a = 0; a < 2; a++)
    #pragma unroll
    for (int c = 0; c < 4; c++) acc[a][c] = zf4();

  int sw = t >> 2, sco = (t & 3) * 16;
  const bf16x8 zero8 = {0,0,0,0,0,0,0,0};

  // prologue: load chunk 0 into regs
  bf16x8 st[3][2];
  #pragma unroll
  for (int r = 0; r < 3; r++){
    int h2 = h + r - 1;
    bool v = (unsigned)h2 < 64u;
    #pragma unroll
    for (int u = 0; u < 2; u++)
      st[r][u] = v ? *(const bf16x8*)(inb + (((size_t)(h2 * 64 + sw)) << 8)
                                      + sco + u * 8)
                   : zero8;
  }

  for (int cc = 0; cc < 256; cc += 64){
    __syncthreads();   // A: previous chunk's Xs reads complete
    #pragma unroll
    for (int r = 0; r < 3; r++)
      #pragma unroll
      for (int u = 0; u < 2; u++)
        *(bf16x8*)(&Xs[r][sw][sco + u * 8]) = st[r][u];
    __syncthreads();   // B: Xs visible
    // issue next chunk's loads now; latency hides under the 36-MFMA section
    if (cc < 192){
      #pragma unroll
      for (int r = 0; r < 3; r++){
        int h2 = h + r - 1;
        bool v = (unsigned)h2 < 64u;
        #pragma unroll
        for (int u = 0; u < 2; u++)
          st[r][u] = v ? *(const bf16x8*)(inb + (((size_t)(h2 * 64 + sw)) << 8)
                                          + cc + 64 + sco + u * 8)
                       : zero8;
      }
    }
    #pragma unroll
    for (int tau = 0; tau < 9; tau++){
      int dy = tau / 3 - 1, dx = tau % 3 - 1;
      #pragma unroll
      for (int kf = 0; kf < 2; kf++){
        bf16x8 af[2];
        #pragma unroll
        for (int of = 0; of < 2; of++)
          af[of] = *(const bf16x8*)(ap + ((size_t)tau << 16)
                     + ((o0 + of * 16 + lr) << 8) + cc + kf * 32 + 8 * g);
        bf16x8 bv[4];
        #pragma unroll
        for (int pf = 0; pf < 4; pf++){
          int wsrc = pf * 16 + lr + dx;
          bv[pf] = ((unsigned)wsrc < 64u)
                 ? *(const bf16x8*)(&Xs[dy + 1][wsrc][kf * 32 + 8 * g])
                 : zero8;
        }
        #pragma unroll
        for (int of = 0; of < 2; of++)
          #pragma unroll
          for (int pf = 0; pf < 4; pf++)
            acc[of][pf] = __builtin_amdgcn_mfma_f32_16x16x32_bf16(af[of], bv[pf], acc[of][pf], 0, 0, 0);
      }
    }
  }
  #pragma unroll
  for (int of = 0; of < 2; of++){
    int ob = o0 + of * 16 + 4 * g;
    #pragma unroll
    for (int pf = 0; pf < 4; pf++){
      int p = h * 64 + pf * 16 + lr;
      #pragma unroll
      for (int i = 0; i < 4; i++){
        int o = ob + i;
        float v = acc[of][pf][i] + bias[o];
        size_t oi = ((size_t)b << 20) + ((size_t)o << 12) + p;
        if (OUTF32) ((float*)outp)[oi] = v;
        else        ((unsigned short*)outp)[oi] = f2bf(v);
      }
    }
  }
}

// ---------------------------------------------------------------------------
// k_pv v5: fused S(fp16)/exp2/PV, m-split, T14 register-staged Xl prefetch.
// Per step: S-MFMA (a0/a1 prefetched) -> exp2 -> barrier A -> ds_write Xl
// (from xst regs) + Pl writes -> barrier B -> ISSUE next step's xst/a loads
// -> PV. Loads land during PV+S+exp (~1400 cyc window).
// LDS 40KB, 4 blocks/CU.
// ---------------------------------------------------------------------------
__global__ __launch_bounds__(256, 4) void k_pv(
    const unsigned short* __restrict__ tT16, const unsigned short* __restrict__ cT16,
    const unsigned short* __restrict__ xbot,
    float* __restrict__ U0, float* __restrict__ U1,
    float* __restrict__ rsum, int nsteps){
  __shared__ unsigned short Pl[64 * 64];    // [n][m-slot ^ (n&7)]
  __shared__ unsigned short Xl[256 * 64];   // [c][m-slot ^ (c&7)]
  int bid = blockIdx.x;
  int b = bid & 7, nt = (bid >> 3) & 63, mh = bid >> 9;
  int t = threadIdx.x, wv = t >> 6, l = t & 63, lr = l & 15, g = l >> 4;
  int n0 = nt * 64;
  const unsigned short* xbb = xbot + ((size_t)b << 20);
  float* Ub = mh ? U1 : U0;

  // cen fp16 frags (loop-invariant): col n = n0+nf*16+lr, k = kf*32+8g..
  f16x8 ch[2][4];
  #pragma unroll
  for (int kf = 0; kf < 2; kf++)
    #pragma unroll
    for (int nf = 0; nf < 4; nf++)
      ch[kf][nf] = *(const f16x8*)(cT16
          + (((size_t)b << 12) + n0 + nf * 16 + lr) * 64 + kf * 32 + 8 * g);

  f32x4 acc[4][4];
  #pragma unroll
  for (int a = 0; a < 4; a++)
    #pragma unroll
    for (int c = 0; c < 4; c++) acc[a][c] = zf4();
  float racc = 0.f;

  // Xl staging map: thread covers rows srow+32j, source chunk pre-swizzled
  // so LDS[row][slot] holds global chunk slot^(row&7); LDS side stays linear.
  int srow = wv * 8 + (l >> 3);
  int scol = (((l & 7) ^ ((l >> 3) & 7)) << 3);
  const unsigned short* gsrc = xbb + ((size_t)srow << 12) + (size_t)mh * 2048 + scol;
  unsigned short* ldst = Xl + srow * 64 + (l & 7) * 8;

  const unsigned short* tb = tT16
      + (((size_t)b << 12) + (size_t)mh * 2048 + wv * 16 + lr) * 64 + 8 * g;

  // prologue: prefetch step 0's A-frags and Xl tile
  f16x8 a0 = *(const f16x8*)(tb);
  f16x8 a1 = *(const f16x8*)(tb + 32);
  bf16x8 xst[8];
  #pragma unroll
  for (int j = 0; j < 8; j++)
    xst[j] = *(const bf16x8*)(gsrc + ((size_t)(32 * j) << 12));

  for (int msi = 0; msi < nsteps; msi++){
    int m0 = msi * 64;
    // --- S (fp16, single term), rows wv*16.., cols n0..+64
    f32x4 sa[4];
    #pragma unroll
    for (int nf = 0; nf < 4; nf++) sa[nf] = zf4();
    #pragma unroll
    for (int nf = 0; nf < 4; nf++)
      sa[nf] = __builtin_amdgcn_mfma_f32_16x16x32_f16(a0, ch[0][nf], sa[nf], 0, 0, 0);
    #pragma unroll
    for (int nf = 0; nf < 4; nf++)
      sa[nf] = __builtin_amdgcn_mfma_f32_16x16x32_f16(a1, ch[1][nf], sa[nf], 0, 0, 0);
    // --- exp2 (top pre-scaled by log2 e; no max-shift) + pack
    unsigned pk[4][2];
    #pragma unroll
    for (int nf = 0; nf < 4; nf++){
      float e0 = __builtin_amdgcn_exp2f(sa[nf][0]);
      float e1 = __builtin_amdgcn_exp2f(sa[nf][1]);
      float e2 = __builtin_amdgcn_exp2f(sa[nf][2]);
      float e3 = __builtin_amdgcn_exp2f(sa[nf][3]);
      racc += (e0 + e1) + (e2 + e3);
      pk[nf][0] = (unsigned)f2bf(e0) | ((unsigned)f2bf(e1) << 16);
      pk[nf][1] = (unsigned)f2bf(e2) | ((unsigned)f2bf(e3) << 16);
    }
    __syncthreads();   // A: previous step's Pl/Xl reads complete
    // --- Xl writes from prefetched regs (linear dest, source was pre-swizzled)
    #pragma unroll
    for (int j = 0; j < 8; j++)
      *(bf16x8*)(ldst + j * 32 * 64) = xst[j];
    // --- Pl writes (xor-swizzled 16B slots, 2x4B stores -> b64)
    #pragma unroll
    for (int nf = 0; nf < 4; nf++){
      int prow = nf * 16 + lr;
      unsigned* pp = (unsigned*)(Pl + prow * 64
          + (((2 * wv + (g >> 1)) ^ (lr & 7)) << 3) + ((g & 1) << 2));
      pp[0] = pk[nf][0];
      pp[1] = pk[nf][1];
    }
    __syncthreads();   // B: staging + Pl visible
    // --- issue NEXT step's loads; land during PV + next S/exp
    if (msi + 1 < nsteps){
      int m1 = m0 + 64;
      a0 = *(const f16x8*)(tb + (size_t)m1 * 64);
      a1 = *(const f16x8*)(tb + (size_t)m1 * 64 + 32);
      #pragma unroll
      for (int j = 0; j < 8; j++)
        xst[j] = *(const bf16x8*)(gsrc + ((size_t)(32 * j) << 12) + m1);
    }
    // --- PV: acc[n, c] += P[n, m-tile] * xbot[m-tile, c]
    #pragma unroll
    for (int kf = 0; kf < 2; kf++){
      bf16x8 pa[4];
      #pragma unroll
      for (int nf = 0; nf < 4; nf++)
        pa[nf] = *(const bf16x8*)(Pl + (nf * 16 + lr) * 64
                   + ((((kf << 2) + g) ^ (lr & 7)) << 3));
      #pragma unroll
      for (int cf = 0; cf < 4; cf++){
        bf16x8 bx = *(const bf16x8*)(Xl + (wv * 64 + cf * 16 + lr) * 64
                   + ((((kf << 2) + g) ^ (lr & 7)) << 3));
        #pragma unroll
        for (int nf = 0; nf < 4; nf++)
          acc[nf][cf] = __builtin_amdgcn_mfma_f32_16x16x32_bf16(pa[nf], bx, acc[nf][cf], 0, 0, 0);
      }
    }
  }
  // --- write unnormalized U partial (flat n*256+c == scrambled reshape)
  #pragma unroll
  for (int nf = 0; nf < 4; nf++)
    #pragma unroll
    for (int cf = 0; cf < 4; cf++)
      #pragma unroll
      for (int i = 0; i < 4; i++){
        int n = n0 + nf * 16 + 4 * g + i;
        int c = wv * 64 + cf * 16 + lr;
        __builtin_nontemporal_store(acc[nf][cf][i],
            &Ub[((size_t)b << 20) + ((size_t)n << 8) + c]);
      }
  // --- Z partial: wave scalar
  racc += __shfl_xor(racc, 1);
  racc += __shfl_xor(racc, 2);
  racc += __shfl_xor(racc, 4);
  racc += __shfl_xor(racc, 8);
  racc += __shfl_xor(racc, 16);
  racc += __shfl_xor(racc, 32);
  if (l == 0) rsum[(size_t)bid * 4 + wv] = racc;
}

// ---------------------------------------------------------------------------
// k_rsum: Z[b] = sum of this batch's wave partials (256*msplit slots)
// ---------------------------------------------------------------------------
__global__ __launch_bounds__(256) void k_rsum(const float* __restrict__ r,
                                              float* __restrict__ Z, int msplit){
  __shared__ float red[256];
  int b = blockIdx.x, t = threadIdx.x;
  int total = 256 * msplit;
  float s = 0.f;
  for (int s2 = t; s2 < total; s2 += 256)
    s += r[(size_t)(b + 8 * (s2 >> 2)) * 4 + (s2 & 3)];
  red[t] = s;
  __syncthreads();
  for (int o = 128; o > 0; o >>= 1){
    if (t < o) red[t] += red[t + o];
    __syncthreads();
  }
  if (t == 0) Z[b] = red[0];
}

// ---------------------------------------------------------------------------
extern "C" void kernel_launch(void* const* d_in, const int* in_sizes, int n_in,
                              void* d_out, int out_size, void* d_ws, size_t ws_size,
                              hipStream_t stream) {
  const float* x     = (const float*)d_in[0];
  const float* top_w = (const float*)d_in[1];
  const float* top_b = (const float*)d_in[2];
  const float* cen_w = (const float*)d_in[3];
  const float* cen_b = (const float*)d_in[4];
  const float* bot_w = (const float*)d_in[5];
  const float* bot_b = (const float*)d_in[6];
  const float* out_w = (const float*)d_in[7];
  const float* out_b = (const float*)d_in[8];
  float* out = (float*)d_out;

  constexpr size_t MB = 1ull << 20;
  // m-split doubles U; gate on available scratch (fallback = single U).
  int msplit = (ws_size >= 108 * MB) ? 2 : 1;

  char* p = (char*)d_ws;
  float* U0 = (float*)p;                       p += 32 * MB;
  float* U1 = nullptr;
  if (msplit == 2){ U1 = (float*)p;            p += 32 * MB; }
  unsigned short* tT16 = (unsigned short*)p;   p += 4 * MB;
  unsigned short* cT16 = (unsigned short*)p;   p += 4 * MB;
  unsigned short* xbot = (unsigned short*)p;   p += 16 * MB;
  unsigned short* xcl  = (unsigned short*)p;   p += 16 * MB;  // reused as ycl
  float* wTt = (float*)p;                      p += 65536;
  float* wTc = (float*)p;                      p += 65536;
  unsigned short* apb = (unsigned short*)p;    p += 1179648;
  unsigned short* apo = (unsigned short*)p;    p += 1179648;
  float* r = (float*)p;                        p += 65536;
  float* Z = (float*)p;

  // 1. weight prep
  k_prep<<<2304, 256, 0, stream>>>(top_w, cen_w, bot_w, out_w, wTt, wTc, apb, apo);
  // 2. top/center 1x1 convs -> fp16 transposed (top pre-scaled by log2 e)
  k_topcenter<<<dim3(16, 2, 8), 256, 0, stream>>>(x, wTt, wTc, top_b, cen_b,
                                                  tT16, cT16);
  // 3. x -> channels-last bf16
  k_trans<<<dim3(128, 8, 8), 256, 0, stream>>>(x, nullptr, nullptr, nullptr, xcl);
  // 4. bottom 3x3 conv -> x_bottom bf16 [b][c][p]
  k_conv3<0><<<dim3(1024), 256, 0, stream>>>(xcl, apb, bot_b, (void*)xbot);
  // 5. fused S/exp/PV -> U partials + wave partials for Z
  k_pv<<<dim3(512 * msplit), 256, 0, stream>>>(tT16, cT16, xbot, U0,
                                               msplit == 2 ? U1 : U0, r,
                                               64 / msplit);
  // 6. Z per batch
  k_rsum<<<8, 256, 0, stream>>>(r, Z, msplit);
  // 7. y = x + (U0+U1)/Z -> ycl bf16
  k_trans<<<dim3(128, 8, 8), 256, 0, stream>>>(x, U0, U1, Z, xcl);
  // 8. final 3x3 conv -> d_out fp32
  k_conv3<1><<<dim3(1024), 256, 0, stream>>>(xcl, apo, out_b, (void*)out);
}

// Round 6
// 377.906 us; speedup vs baseline: 1.6460x; 1.6460x over previous
//
#include <hip/hip_runtime.h>

// B=8, C=256, K=64, H=W=64, HW=4096
using bf16x8 = __attribute__((ext_vector_type(8))) short;
using f16x8  = __attribute__((ext_vector_type(8))) _Float16;
using f32x4  = __attribute__((ext_vector_type(4))) float;

#define DEVI static __device__ __forceinline__

DEVI unsigned short f2bf(float f){
  unsigned u = __builtin_bit_cast(unsigned, f);
  u += 0x7fffu + ((u >> 16) & 1u);
  return (unsigned short)(u >> 16);
}
DEVI unsigned short f2h(float f){
  _Float16 h = (_Float16)f;
  return __builtin_bit_cast(unsigned short, h);
}
DEVI f32x4 zf4(){ f32x4 z; z[0]=0.f; z[1]=0.f; z[2]=0.f; z[3]=0.f; return z; }

// ---------------------------------------------------------------------------
// k_prep: transpose 1x1 weights to [c][k]; pack 3x3 weights to [tau][o][c] bf16
// ---------------------------------------------------------------------------
__global__ __launch_bounds__(256) void k_prep(
    const float* __restrict__ top_w, const float* __restrict__ cen_w,
    const float* __restrict__ bot_w, const float* __restrict__ out_w,
    float* __restrict__ wTt, float* __restrict__ wTc,
    unsigned short* __restrict__ apb, unsigned short* __restrict__ apo){
  int i = blockIdx.x * 256 + threadIdx.x;
  if (i < 64 * 256){
    int c = i >> 6, k = i & 63;
    wTt[i] = top_w[k * 256 + c];
    wTc[i] = cen_w[k * 256 + c];
  }
  if (i < 9 * 256 * 256){
    int tau = i >> 16, oc = i & 65535;   // oc = o*256+c
    apb[i] = f2bf(bot_w[oc * 9 + tau]);
    apo[i] = f2bf(out_w[oc * 9 + tau]);
  }
}

// ---------------------------------------------------------------------------
// k_topcenter: top/center = W[64,256] @ x[256,4096] per batch, fp32 VALU,
// stored transposed [n][k] as fp16. top pre-scaled by log2(e) so the
// softmax exp becomes a single v_exp_f32 (exp2) in k_pv.
// ---------------------------------------------------------------------------
__global__ __launch_bounds__(256) void k_topcenter(
    const float* __restrict__ x,
    const float* __restrict__ wTt, const float* __restrict__ wTc,
    const float* __restrict__ top_b, const float* __restrict__ cen_b,
    unsigned short* __restrict__ tT16, unsigned short* __restrict__ cT16){
  __shared__ float xs[16][256];
  int b = blockIdx.z, z = blockIdx.y, nt = blockIdx.x;
  int t = threadIdx.x;
  int n = nt * 256 + t;
  const float* wT   = z ? wTc : wTt;
  const float* bias = z ? cen_b : top_b;
  unsigned short* o16 = z ? cT16 : tT16;
  const float scale = z ? 1.0f : 1.4426950408889634f;   // log2(e) folded into top
  const float* xb = x + ((size_t)b << 20);

  float acc[64];
  #pragma unroll
  for (int k = 0; k < 64; k++) acc[k] = 0.f;

  for (int cc = 0; cc < 256; cc += 16){
    __syncthreads();
    #pragma unroll
    for (int r = 0; r < 16; r++)
      xs[r][t] = xb[((size_t)(cc + r) << 12) + nt * 256 + t];
    __syncthreads();
    #pragma unroll
    for (int r = 0; r < 16; r++){
      float xv = xs[r][t];
      const float* wr = wT + (cc + r) * 64;   // uniform -> scalar loads
      #pragma unroll
      for (int k = 0; k < 64; k++) acc[k] = fmaf(wr[k], xv, acc[k]);
    }
  }
  size_t base = (((size_t)b << 12) + n) * 64;
  #pragma unroll
  for (int k8 = 0; k8 < 64; k8 += 8){
    bf16x8 v8;
    #pragma unroll
    for (int j = 0; j < 8; j++)
      v8[j] = (short)f2h((acc[k8 + j] + bias[k8 + j]) * scale);
    *(bf16x8*)(o16 + base + k8) = v8;
  }
}

// ---------------------------------------------------------------------------
// k_trans: channels-first fp32 (+ optional (U0+U1)/Z residual) -> ch-last bf16
// ---------------------------------------------------------------------------
__global__ __launch_bounds__(256) void k_trans(
    const float* __restrict__ x, const float* __restrict__ U0,
    const float* __restrict__ U1, const float* __restrict__ Z,
    unsigned short* __restrict__ ocl){
  __shared__ float tile[32][33];
  int b = blockIdx.z, ct = blockIdx.y, pt = blockIdx.x;
  int tx = threadIdx.x & 31, ty = threadIdx.x >> 5;
  size_t bo = (size_t)b << 20;
  int c0 = ct * 32, p0 = pt * 32;
  float invZ = (U0 != nullptr) ? (1.0f / Z[b]) : 0.0f;
  #pragma unroll
  for (int q = 0; q < 4; q++){
    int c = c0 + ty + q * 8;
    size_t idx = bo + ((size_t)c << 12) + p0 + tx;
    float v = x[idx];
    if (U0){
      float u = U0[idx];
      if (U1) u += U1[idx];
      v = fmaf(u, invZ, v);
    }
    tile[ty + q * 8][tx] = v;
  }
  __syncthreads();
  #pragma unroll
  for (int q = 0; q < 4; q++){
    int p = p0 + ty + q * 8;
    ocl[bo + ((size_t)p << 8) + c0 + tx] = f2bf(tile[tx][ty + q * 8]);
  }
}

// ---------------------------------------------------------------------------
// k_conv3: 3x3 SAME conv, halo-row staging reused across 9 taps,
// T14 async-stage: next chunk's global loads issue BEFORE the MFMA section.
// Block: (b, image row h, o-half). 256 thr / 4 waves; wave owns 32 o.
// ---------------------------------------------------------------------------
template<int OUTF32>
__global__ __launch_bounds__(256, 4) void k_conv3(
    const unsigned short* __restrict__ incl,
    const unsigned short* __restrict__ ap,
    const float* __restrict__ bias, void* __restrict__ outp){
  __shared__ unsigned short Xs[3][64][72];   // [halo row][w][c-chunk], 144B rows
  int bid = blockIdx.x;
  int b = bid & 7, h = (bid >> 3) & 63, oh = bid >> 9;
  int t = threadIdx.x, wv = t >> 6, l = t & 63, lr = l & 15, g = l >> 4;
  int o0 = oh * 128 + wv * 32;
  const unsigned short* inb = incl + ((size_t)b << 20);

  f32x4 acc[2][4];
  #pragma unroll
  for (int a = 0; a < 2; a++)
    #pragma unroll
    for (int c = 0; c < 4; c++) acc[a][c] = zf4();

  int sw = t >> 2, sco = (t & 3) * 16;
  const bf16x8 zero8 = {0,0,0,0,0,0,0,0};

  // prologue: load chunk 0 into regs
  bf16x8 st[3][2];
  #pragma unroll
  for (int r = 0; r < 3; r++){
    int h2 = h + r - 1;
    bool v = (unsigned)h2 < 64u;
    #pragma unroll
    for (int u = 0; u < 2; u++)
      st[r][u] = v ? *(const bf16x8*)(inb + (((size_t)(h2 * 64 + sw)) << 8)
                                      + sco + u * 8)
                   : zero8;
  }

  for (int cc = 0; cc < 256; cc += 64){
    __syncthreads();   // A: previous chunk's Xs reads complete
    #pragma unroll
    for (int r = 0; r < 3; r++)
      #pragma unroll
      for (int u = 0; u < 2; u++)
        *(bf16x8*)(&Xs[r][sw][sco + u * 8]) = st[r][u];
    __syncthreads();   // B: Xs visible
    // issue next chunk's loads now; latency hides under the 36-MFMA section
    if (cc < 192){
      #pragma unroll
      for (int r = 0; r < 3; r++){
        int h2 = h + r - 1;
        bool v = (unsigned)h2 < 64u;
        #pragma unroll
        for (int u = 0; u < 2; u++)
          st[r][u] = v ? *(const bf16x8*)(inb + (((size_t)(h2 * 64 + sw)) << 8)
                                          + cc + 64 + sco + u * 8)
                       : zero8;
      }
    }
    #pragma unroll
    for (int tau = 0; tau < 9; tau++){
      int dy = tau / 3 - 1, dx = tau % 3 - 1;
      #pragma unroll
      for (int kf = 0; kf < 2; kf++){
        bf16x8 af[2];
        #pragma unroll
        for (int of = 0; of < 2; of++)
          af[of] = *(const bf16x8*)(ap + ((size_t)tau << 16)
                     + ((o0 + of * 16 + lr) << 8) + cc + kf * 32 + 8 * g);
        bf16x8 bv[4];
        #pragma unroll
        for (int pf = 0; pf < 4; pf++){
          int wsrc = pf * 16 + lr + dx;
          bv[pf] = ((unsigned)wsrc < 64u)
                 ? *(const bf16x8*)(&Xs[dy + 1][wsrc][kf * 32 + 8 * g])
                 : zero8;
        }
        #pragma unroll
        for (int of = 0; of < 2; of++)
          #pragma unroll
          for (int pf = 0; pf < 4; pf++)
            acc[of][pf] = __builtin_amdgcn_mfma_f32_16x16x32_bf16(af[of], bv[pf], acc[of][pf], 0, 0, 0);
      }
    }
  }
  #pragma unroll
  for (int of = 0; of < 2; of++){
    int ob = o0 + of * 16 + 4 * g;
    #pragma unroll
    for (int pf = 0; pf < 4; pf++){
      int p = h * 64 + pf * 16 + lr;
      #pragma unroll
      for (int i = 0; i < 4; i++){
        int o = ob + i;
        float v = acc[of][pf][i] + bias[o];
        size_t oi = ((size_t)b << 20) + ((size_t)o << 12) + p;
        if (OUTF32) ((float*)outp)[oi] = v;
        else        ((unsigned short*)outp)[oi] = f2bf(v);
      }
    }
  }
}

// ---------------------------------------------------------------------------
// k_pv v6: fused S(fp16)/exp2/PV, m-split, double-buffered LDS pipeline.
// Per iteration t: issue global_load_lds -> Xl[nxt] (step t+1, zero VGPR),
// compute S(t+1) into regs (a-frags prefetched t-1), PV(t) from buf[cur],
// write Pl[nxt], ONE __syncthreads. Loads span the whole S+PV phase.
// LDS 80KB -> 2 blocks/CU; launch_bounds(256,2) -> 256-reg cap, no spill.
// ---------------------------------------------------------------------------
__global__ __launch_bounds__(256, 2) void k_pv(
    const unsigned short* __restrict__ tT16, const unsigned short* __restrict__ cT16,
    const unsigned short* __restrict__ xbot,
    float* __restrict__ U0, float* __restrict__ U1,
    float* __restrict__ rsum, int nsteps){
  __shared__ unsigned short Pl[2][64 * 64];    // [n][m-slot ^ (n&7)]
  __shared__ unsigned short Xl[2][256 * 64];   // [c][m-slot ^ (c&7)]
  int bid = blockIdx.x;
  int b = bid & 7, nt = (bid >> 3) & 63, mh = bid >> 9;
  int t = threadIdx.x, wv = t >> 6, l = t & 63, lr = l & 15, g = l >> 4;
  int n0 = nt * 64;
  const unsigned short* xbb = xbot + ((size_t)b << 20);
  float* Ub = mh ? U1 : U0;

  // cen fp16 frags (loop-invariant): col n = n0+nf*16+lr, k = kf*32+8g..
  f16x8 ch[2][4];
  #pragma unroll
  for (int kf = 0; kf < 2; kf++)
    #pragma unroll
    for (int nf = 0; nf < 4; nf++)
      ch[kf][nf] = *(const f16x8*)(cT16
          + (((size_t)b << 12) + n0 + nf * 16 + lr) * 64 + kf * 32 + 8 * g);

  f32x4 acc[4][4];
  #pragma unroll
  for (int a = 0; a < 4; a++)
    #pragma unroll
    for (int c = 0; c < 4; c++) acc[a][c] = zf4();
  float racc = 0.f;
  unsigned pk[4][2];

  // Xl staging map (global_load_lds: LDS dest wave-uniform base + lane*16B).
  // LDS[row][slot] = global[row][slot ^ (row&7)] via pre-swizzled SOURCE col.
  int srow = wv * 8 + (l >> 3);
  const unsigned short* gstage = xbb + ((size_t)srow << 12) + (size_t)mh * 2048
      + (((l & 7) ^ ((l >> 3) & 7)) << 3);

  const unsigned short* tb = tT16
      + (((size_t)b << 12) + (size_t)mh * 2048 + wv * 16 + lr) * 64 + 8 * g;

  auto gll = [&](int buf, int step){
    const unsigned short* gs = gstage + (size_t)step * 64;
    #pragma unroll
    for (int j = 0; j < 8; j++)
      __builtin_amdgcn_global_load_lds(
          (const __attribute__((address_space(1))) void*)(gs + ((size_t)(32 * j) << 12)),
          (__attribute__((address_space(3))) void*)(&Xl[buf][(wv * 8 + j * 32) * 64]),
          16, 0, 0);
  };

  auto sphase = [&](f16x8 A0, f16x8 A1){
    f32x4 sa[4];
    #pragma unroll
    for (int nf = 0; nf < 4; nf++) sa[nf] = zf4();
    #pragma unroll
    for (int nf = 0; nf < 4; nf++)
      sa[nf] = __builtin_amdgcn_mfma_f32_16x16x32_f16(A0, ch[0][nf], sa[nf], 0, 0, 0);
    #pragma unroll
    for (int nf = 0; nf < 4; nf++)
      sa[nf] = __builtin_amdgcn_mfma_f32_16x16x32_f16(A1, ch[1][nf], sa[nf], 0, 0, 0);
    #pragma unroll
    for (int nf = 0; nf < 4; nf++){
      float e0 = __builtin_amdgcn_exp2f(sa[nf][0]);
      float e1 = __builtin_amdgcn_exp2f(sa[nf][1]);
      float e2 = __builtin_amdgcn_exp2f(sa[nf][2]);
      float e3 = __builtin_amdgcn_exp2f(sa[nf][3]);
      racc += (e0 + e1) + (e2 + e3);
      pk[nf][0] = (unsigned)f2bf(e0) | ((unsigned)f2bf(e1) << 16);
      pk[nf][1] = (unsigned)f2bf(e2) | ((unsigned)f2bf(e3) << 16);
    }
  };

  auto plwrite = [&](int buf){
    #pragma unroll
    for (int nf = 0; nf < 4; nf++){
      unsigned* pp = (unsigned*)(&Pl[buf][(nf * 16 + lr) * 64
          + (((2 * wv + (g >> 1)) ^ (lr & 7)) << 3) + ((g & 1) << 2)]);
      pp[0] = pk[nf][0];
      pp[1] = pk[nf][1];
    }
  };

  auto pv = [&](int buf){
    #pragma unroll
    for (int kf = 0; kf < 2; kf++){
      bf16x8 pa[4];
      #pragma unroll
      for (int nf = 0; nf < 4; nf++)
        pa[nf] = *(const bf16x8*)(&Pl[buf][(nf * 16 + lr) * 64
                   + ((((kf << 2) + g) ^ (lr & 7)) << 3)]);
      #pragma unroll
      for (int cf = 0; cf < 4; cf++){
        bf16x8 bx = *(const bf16x8*)(&Xl[buf][(wv * 64 + cf * 16 + lr) * 64
                   + ((((kf << 2) + g) ^ (lr & 7)) << 3)]);
        #pragma unroll
        for (int nf = 0; nf < 4; nf++)
          acc[nf][cf] = __builtin_amdgcn_mfma_f32_16x16x32_bf16(pa[nf], bx, acc[nf][cf], 0, 0, 0);
      }
    }
  };

  // prologue: stage step 0 (Xl buf0 + Pl buf0), prefetch step-1 A-frags
  f16x8 a0 = *(const f16x8*)(tb);
  f16x8 a1 = *(const f16x8*)(tb + 32);
  gll(0, 0);
  sphase(a0, a1);          // step 0 -> pk
  a0 = *(const f16x8*)(tb + (size_t)4096);
  a1 = *(const f16x8*)(tb + (size_t)4096 + 32);
  plwrite(0);
  __syncthreads();

  for (int ms = 0; ms < nsteps; ms++){
    int cur = ms & 1, nxt = cur ^ 1;
    if (ms + 1 < nsteps){
      gll(nxt, ms + 1);        // issue first: in flight across S + PV
      sphase(a0, a1);          // S for step ms+1 -> pk
      if (ms + 2 < nsteps){
        a0 = *(const f16x8*)(tb + (size_t)(ms + 2) * 4096);
        a1 = *(const f16x8*)(tb + (size_t)(ms + 2) * 4096 + 32);
      }
    }
    pv(cur);                   // 16 ds_read + 32 MFMA on current buffers
    if (ms + 1 < nsteps) plwrite(nxt);
    __syncthreads();           // one barrier/step: drains gll + Pl writes
  }

  // --- write unnormalized U partial (flat n*256+c == scrambled reshape)
  #pragma unroll
  for (int nf = 0; nf < 4; nf++)
    #pragma unroll
    for (int cf = 0; cf < 4; cf++)
      #pragma unroll
      for (int i = 0; i < 4; i++){
        int n = n0 + nf * 16 + 4 * g + i;
        int c = wv * 64 + cf * 16 + lr;
        __builtin_nontemporal_store(acc[nf][cf][i],
            &Ub[((size_t)b << 20) + ((size_t)n << 8) + c]);
      }
  // --- Z partial: wave scalar
  racc += __shfl_xor(racc, 1);
  racc += __shfl_xor(racc, 2);
  racc += __shfl_xor(racc, 4);
  racc += __shfl_xor(racc, 8);
  racc += __shfl_xor(racc, 16);
  racc += __shfl_xor(racc, 32);
  if (l == 0) rsum[(size_t)bid * 4 + wv] = racc;
}

// ---------------------------------------------------------------------------
// k_rsum: Z[b] = sum of this batch's wave partials (256*msplit slots)
// ---------------------------------------------------------------------------
__global__ __launch_bounds__(256) void k_rsum(const float* __restrict__ r,
                                              float* __restrict__ Z, int msplit){
  __shared__ float red[256];
  int b = blockIdx.x, t = threadIdx.x;
  int total = 256 * msplit;
  float s = 0.f;
  for (int s2 = t; s2 < total; s2 += 256)
    s += r[(size_t)(b + 8 * (s2 >> 2)) * 4 + (s2 & 3)];
  red[t] = s;
  __syncthreads();
  for (int o = 128; o > 0; o >>= 1){
    if (t < o) red[t] += red[t + o];
    __syncthreads();
  }
  if (t == 0) Z[b] = red[0];
}

// ---------------------------------------------------------------------------
extern "C" void kernel_launch(void* const* d_in, const int* in_sizes, int n_in,
                              void* d_out, int out_size, void* d_ws, size_t ws_size,
                              hipStream_t stream) {
  const float* x     = (const float*)d_in[0];
  const float* top_w = (const float*)d_in[1];
  const float* top_b = (const float*)d_in[2];
  const float* cen_w = (const float*)d_in[3];
  const float* cen_b = (const float*)d_in[4];
  const float* bot_w = (const float*)d_in[5];
  const float* bot_b = (const float*)d_in[6];
  const float* out_w = (const float*)d_in[7];
  const float* out_b = (const float*)d_in[8];
  float* out = (float*)d_out;

  constexpr size_t MB = 1ull << 20;
  // m-split doubles U; gate on available scratch (fallback = single U).
  int msplit = (ws_size >= 108 * MB) ? 2 : 1;

  char* p = (char*)d_ws;
  float* U0 = (float*)p;                       p += 32 * MB;
  float* U1 = nullptr;
  if (msplit == 2){ U1 = (float*)p;            p += 32 * MB; }
  unsigned short* tT16 = (unsigned short*)p;   p += 4 * MB;
  unsigned short* cT16 = (unsigned short*)p;   p += 4 * MB;
  unsigned short* xbot = (unsigned short*)p;   p += 16 * MB;
  unsigned short* xcl  = (unsigned short*)p;   p += 16 * MB;  // reused as ycl
  float* wTt = (float*)p;                      p += 65536;
  float* wTc = (float*)p;                      p += 65536;
  unsigned short* apb = (unsigned short*)p;    p += 1179648;
  unsigned short* apo = (unsigned short*)p;    p += 1179648;
  float* r = (float*)p;                        p += 65536;
  float* Z = (float*)p;

  // 1. weight prep
  k_prep<<<2304, 256, 0, stream>>>(top_w, cen_w, bot_w, out_w, wTt, wTc, apb, apo);
  // 2. top/center 1x1 convs -> fp16 transposed (top pre-scaled by log2 e)
  k_topcenter<<<dim3(16, 2, 8), 256, 0, stream>>>(x, wTt, wTc, top_b, cen_b,
                                                  tT16, cT16);
  // 3. x -> channels-last bf16
  k_trans<<<dim3(128, 8, 8), 256, 0, stream>>>(x, nullptr, nullptr, nullptr, xcl);
  // 4. bottom 3x3 conv -> x_bottom bf16 [b][c][p]
  k_conv3<0><<<dim3(1024), 256, 0, stream>>>(xcl, apb, bot_b, (void*)xbot);
  // 5. fused S/exp/PV -> U partials + wave partials for Z
  k_pv<<<dim3(512 * msplit), 256, 0, stream>>>(tT16, cT16, xbot, U0,
                                               msplit == 2 ? U1 : U0, r,
                                               64 / msplit);
  // 6. Z per batch
  k_rsum<<<8, 256, 0, stream>>>(r, Z, msplit);
  // 7. y = x + (U0+U1)/Z -> ycl bf16
  k_trans<<<dim3(128, 8, 8), 256, 0, stream>>>(x, U0, U1, Z, xcl);
  // 8. final 3x3 conv -> d_out fp32
  k_conv3<1><<<dim3(1024), 256, 0, stream>>>(xcl, apo, out_b, (void*)out);
}